// Round 3
// baseline (186.712 us; speedup 1.0000x reference)
//
#include <hip/hip_runtime.h>

// EncoderDecoderLSTM fused kernel for MI355X (gfx950).
//
// Math: state never updates, h0=c0=0  =>
//   gates = input @ (W_ih @ enc_W)^T + (W_ih @ enc_b + b_ih + b_hh)
//   f-gate is dead (multiplies c0=0). Only i,g,o needed (768 of 1024 rows).
//   c = sigmoid(i)*tanh(g) = (E-1)/((1+U)(1+E)),  U=e^-i, E=e^2g
//   h = sigmoid(o) * tanhpoly(c)      (|c|<1 -> degree-11 odd poly, no trans)
//   out = h @ dec_W^T + dec_b
//
// R3: 64 t per wave (4 s-subtiles) -> weight loads amortized 2x more, and
// the 4 independent s-chains overlap; single lgkmcnt(0) per hc (batched
// write-all / read-all LDS handoff) removes 3 of 4 serialization points.

typedef _Float16 f16x8 __attribute__((ext_vector_type(8)));
typedef _Float16 f16x4 __attribute__((ext_vector_type(4)));
typedef float    f32x4 __attribute__((ext_vector_type(4)));
typedef __fp16   h16x2 __attribute__((ext_vector_type(2)));

#define T_IN 2048
#define TT   2112   // T + future_n
#define FIN  32
#define FOUT 32
#define NS   4      // 16-row time subtiles per wave (64 t / wave)

// ws layout (bytes): Mb @0 (49152), fb @49152 (3072), decWb @52224 (16384)
#define WS_FB_OFF   49152
#define WS_DECW_OFF 52224

union PkU { h16x2 h; unsigned u; };

__global__ __launch_bounds__(256) void prep2(
    const float* __restrict__ enc_W, const float* __restrict__ enc_b,
    const float* __restrict__ W_ih, const float* __restrict__ b_ih,
    const float* __restrict__ b_hh, const float* __restrict__ dec_W,
    _Float16* __restrict__ Mb, float* __restrict__ fb, _Float16* __restrict__ decWb) {
    const int blk = blockIdx.x;
    const int tid = threadIdx.x;
    if (blk < 768) {
        // row gg: 0-255 = i (sg=gg), 256-511 = g (sg=gg+256), 512-767 = o
        const int gg = blk, sg = gg + (gg >= 256 ? 256 : 0);
        const float* wr = W_ih + (size_t)sg * 256;
        const int f = tid & 31, r8 = tid >> 5;
        float acc = 0.f;
#pragma unroll
        for (int k = 0; k < 32; ++k) {
            int r = r8 * 32 + k;
            acc = fmaf(wr[r], enc_W[r * 32 + f], acc);
        }
        __shared__ float red[256];
        __shared__ float redb[256];
        __shared__ float red2[32];
        red[tid]  = acc;
        redb[tid] = wr[tid] * enc_b[tid];
        __syncthreads();
        if (tid < 32) {
            float s = 0.f;
#pragma unroll
            for (int k = 0; k < 8; ++k) s += red[k * 32 + tid];
            Mb[gg * 32 + tid] = (_Float16)s;
        } else if (tid >= 128 && tid < 160) {
            int t2 = tid - 128;
            float s2 = 0.f;
#pragma unroll
            for (int k = 0; k < 8; ++k) s2 += redb[t2 * 8 + k];
            red2[t2] = s2;
        }
        __syncthreads();
        if (tid == 0) {
            float t = b_ih[sg] + b_hh[sg];
#pragma unroll
            for (int k = 0; k < 32; ++k) t += red2[k];
            fb[gg] = t;
        }
    } else {
        // blocks 768..775: dec_W f32 -> f16 (8192 elems, 4/thread)
        int i = (blk - 768) * 1024 + tid * 4;
        f32x4 v = *(const f32x4*)(dec_W + i);
        f16x4 o;
#pragma unroll
        for (int j = 0; j < 4; ++j) o[j] = (_Float16)v[j];
        *(f16x4*)(decWb + i) = o;
    }
}

__global__ __launch_bounds__(256, 2) void lstm_main(
    const float* __restrict__ in, const _Float16* __restrict__ Mb,
    const float* __restrict__ fb, const _Float16* __restrict__ decWb,
    const float* __restrict__ dec_b, float* __restrict__ out) {
    // per-wave LDS: h tile [NS][16 t][40 f16] (pitch 40: 2-way alias = free)
    __shared__ _Float16 hbuf[4][NS][16 * 40];

    const int lane = threadIdx.x & 63;
    const int w    = threadIdx.x >> 6;
    const int l16  = lane & 15;
    const int q    = lane >> 4;
    const int wave = blockIdx.x * 4 + w;
    const int rowbase = wave * (16 * NS);     // 2112 % 64 == 0: one b per wave
    const int b  = rowbase / TT;
    const int t0 = rowbase - b * TT;

    // Input B-fragments: B[k=q*8+j][n=l16] = input[b][min(t,2047)][q*8+j]
    f16x8 bfr[NS];
#pragma unroll
    for (int s = 0; s < NS; ++s) {
        int t  = t0 + s * 16 + l16;
        int tr = t < T_IN ? t : (T_IN - 1);
        const float* p = in + ((size_t)(b * T_IN + tr)) * FIN + q * 8;
        f32x4 u0 = *(const f32x4*)(p);
        f32x4 u1 = *(const f32x4*)(p + 4);
        PkU c0, c1, c2, c3;
        c0.h = __builtin_amdgcn_cvt_pkrtz(u0[0], u0[1]);
        c1.h = __builtin_amdgcn_cvt_pkrtz(u0[2], u0[3]);
        c2.h = __builtin_amdgcn_cvt_pkrtz(u1[0], u1[1]);
        c3.h = __builtin_amdgcn_cvt_pkrtz(u1[2], u1[3]);
        union { f16x8 v; uint4 u; } pk;
        pk.u = (uint4){ c0.u, c1.u, c2.u, c3.u };
        bfr[s] = pk.v;
    }

    // decoder acc starts at dec_b (rides the MFMA C operand)
    f32x4 dacc[NS][2];
#pragma unroll
    for (int ot = 0; ot < 2; ++ot) {
        f32x4 db = *(const f32x4*)(dec_b + ot * 16 + q * 4);
#pragma unroll
        for (int s = 0; s < NS; ++s) dacc[s][ot] = db;
    }

    for (int hc = 0; hc < 8; ++hc) {
        const int hb = hc * 32;
        // Gate weight A-frags + bias C-frags (shared across all NS subtiles)
        f16x8 afr[3][2];
        f32x4 fbv[3][2];
#pragma unroll
        for (int gt = 0; gt < 3; ++gt)
#pragma unroll
            for (int X = 0; X < 2; ++X) {
                int grow = gt * 256 + hb + X * 16;
                afr[gt][X] = *(const f16x8*)(Mb + (size_t)(grow + l16) * 32 + q * 8);
                fbv[gt][X] = *(const f32x4*)(fb + grow + q * 4);
            }
        // Decoder A-frags: A2[m=ot*16+l16][k -> hid=hb+q*8+j]
        f16x8 a2[2];
#pragma unroll
        for (int ot = 0; ot < 2; ++ot)
            a2[ot] = *(const f16x8*)(decWb + (size_t)(ot * 16 + l16) * 256 + hb + q * 8);

        // Pass 1: gates + activation + LDS writes for ALL subtiles
#pragma unroll
        for (int s = 0; s < NS; ++s) {
            f32x4 gi[2], gg[2], go[2];
#pragma unroll
            for (int X = 0; X < 2; ++X) {
                gi[X] = __builtin_amdgcn_mfma_f32_16x16x32_f16(afr[0][X], bfr[s], fbv[0][X], 0, 0, 0);
                gg[X] = __builtin_amdgcn_mfma_f32_16x16x32_f16(afr[1][X], bfr[s], fbv[1][X], 0, 0, 0);
                go[X] = __builtin_amdgcn_mfma_f32_16x16x32_f16(afr[2][X], bfr[s], fbv[2][X], 0, 0, 0);
            }
            _Float16* hp = &hbuf[w][s][0];
#pragma unroll
            for (int X = 0; X < 2; ++X) {
                float hv[4];
#pragma unroll
                for (int r = 0; r < 4; ++r) {
                    float iv = gi[X][r], gv = gg[X][r], ov = go[X][r];
                    // c = sigmoid(i)*tanh(g) = (E-1)/((1+U)(1+E)); saturations
                    // resolve via rcp(inf)=0; single clamp keeps E finite.
                    float U  = __builtin_amdgcn_exp2f(-1.4426950408889634f * iv);
                    float gc = fminf(gv, 30.f);
                    float E  = __builtin_amdgcn_exp2f(2.8853900817779268f * gc);
                    float c  = (E - 1.0f) * __builtin_amdgcn_rcpf((1.0f + U) * (1.0f + E));
                    // tanh(c), |c|<1: odd Cephes poly, no trans ops
                    float z  = c * c;
                    float P  = fmaf(z, fmaf(z, fmaf(z, fmaf(z, -5.70498872745e-3f,
                                    2.06390887954e-2f), -5.37397155531e-2f),
                                    1.33314422036e-1f), -3.33332819422e-1f);
                    float tc = fmaf(c * z, P, c);
                    float Uo = __builtin_amdgcn_exp2f(-1.4426950408889634f * ov);
                    float so = __builtin_amdgcn_rcpf(1.0f + Uo);
                    hv[r] = so * tc;
                }
                // pack 4 f16 -> one 8B LDS write: h[t=l16][X*16 + q*4 + r]
                PkU p0, p1;
                p0.h = __builtin_amdgcn_cvt_pkrtz(hv[0], hv[1]);
                p1.h = __builtin_amdgcn_cvt_pkrtz(hv[2], hv[3]);
                uint2 wv = { p0.u, p1.u };
                *(uint2*)(hp + l16 * 40 + X * 16 + q * 4) = wv;
            }
        }

        // One drain for all NS subtiles' writes (wave-internal handoff)
        asm volatile("s_waitcnt lgkmcnt(0)" ::: "memory");

        // Pass 2: decoder MFMAs for ALL subtiles
#pragma unroll
        for (int s = 0; s < NS; ++s) {
            const _Float16* hp = &hbuf[w][s][0];
            // B2[k=q*8+j][n=l16] = h[t=l16][hb + q*8+j]
            f16x8 b2 = *(const f16x8*)(hp + l16 * 40 + q * 8);
#pragma unroll
            for (int ot = 0; ot < 2; ++ot)
                dacc[s][ot] = __builtin_amdgcn_mfma_f32_16x16x32_f16(a2[ot], b2, dacc[s][ot], 0, 0, 0);
        }
    }

    // D2[od = ot*16 + 4q + r][t=l16] -> out[(b*TT+t)*32 + od], float4 per lane
#pragma unroll
    for (int s = 0; s < NS; ++s) {
        int t = t0 + s * 16 + l16;
        size_t ro = ((size_t)(b * TT + t)) * FOUT;
#pragma unroll
        for (int ot = 0; ot < 2; ++ot)
            *(f32x4*)(out + ro + ot * 16 + q * 4) = dacc[s][ot];
    }
}

extern "C" void kernel_launch(void* const* d_in, const int* in_sizes, int n_in,
                              void* d_out, int out_size, void* d_ws, size_t ws_size,
                              hipStream_t stream) {
    const float* input = (const float*)d_in[0];
    const float* enc_W = (const float*)d_in[1];
    const float* enc_b = (const float*)d_in[2];
    const float* W_ih  = (const float*)d_in[3];
    // d_in[4] = W_hh: unused (h0 = 0 -> state_gates = b_hh only)
    const float* b_ih  = (const float*)d_in[5];
    const float* b_hh  = (const float*)d_in[6];
    const float* dec_W = (const float*)d_in[7];
    const float* dec_b = (const float*)d_in[8];
    // d_in[9] = future_n (fixed 64, baked into TT)

    _Float16* Mb    = (_Float16*)d_ws;
    float*    fb    = (float*)((char*)d_ws + WS_FB_OFF);
    _Float16* decWb = (_Float16*)((char*)d_ws + WS_DECW_OFF);
    float*    out   = (float*)d_out;

    prep2<<<776, 256, 0, stream>>>(enc_W, enc_b, W_ih, b_ih, b_hh, dec_W, Mb, fb, decWb);
    // 128 b * 2112 t rows / 64 rows-per-wave = 4224 waves; 4 waves/block
    lstm_main<<<1056, 256, 0, stream>>>(input, Mb, fb, decWb, dec_b, out);
}

// Round 4
// 170.117 us; speedup vs baseline: 1.0976x; 1.0976x over previous
//
#include <hip/hip_runtime.h>

// EncoderDecoderLSTM fused kernel for MI355X (gfx950).
//
// Math: state never updates, h0=c0=0  =>
//   gates = input @ (W_ih @ enc_W)^T + (W_ih @ enc_b + b_ih + b_hh)
//   f-gate dead (multiplies c0=0). Only i,g,o needed (768 of 1024 rows).
//   h = sigmoid(o) * tanh( sigmoid(i) * tanh(g) ),  out = h @ dec_W^T + dec_b
//
// R4: transcendental-free activation. sigma(x)=0.5(1+tanh(x/2)); tanh via
// Pade[7/6] rational on clamped u=x/4 in [-1,1] (err<9e-4). Gate pre-scales
// (i,o: /8; g: /4) folded into fused weights+biases. The 3 denominators
// merge into ONE f32 rcp/element; all other activation math is packed f16
// (v_pk_fma_f16: 2 elems/instr). tanh(c),|c|<1: cubic-in-z Chebyshev fit.
// Structure = R2 skeleton (NS=2, 8448 waves) which beat the NS=4 variant.

typedef _Float16 f16x8 __attribute__((ext_vector_type(8)));
typedef _Float16 f16x4 __attribute__((ext_vector_type(4)));
typedef float    f32x4 __attribute__((ext_vector_type(4)));
typedef _Float16 hx2   __attribute__((ext_vector_type(2)));
typedef __fp16   pk16x2 __attribute__((ext_vector_type(2)));

#define T_IN 2048
#define TT   2112   // T + future_n
#define FIN  32
#define FOUT 32

// ws layout (bytes): Mb @0 (49152), fb @49152 (3072), decWb @52224 (16384)
#define WS_FB_OFF   49152
#define WS_DECW_OFF 52224

union PkCast { pk16x2 p; hx2 h; unsigned u; };

__device__ __forceinline__ hx2 pk2(float a, float b) {
    PkCast c; c.p = __builtin_amdgcn_cvt_pkrtz(a, b); return c.h;
}
__device__ __forceinline__ hx2 splat(float v) {
    _Float16 h = (_Float16)v; return (hx2){h, h};
}

__global__ __launch_bounds__(256) void prep2(
    const float* __restrict__ enc_W, const float* __restrict__ enc_b,
    const float* __restrict__ W_ih, const float* __restrict__ b_ih,
    const float* __restrict__ b_hh, const float* __restrict__ dec_W,
    _Float16* __restrict__ Mb, float* __restrict__ fb, _Float16* __restrict__ decWb) {
    const int blk = blockIdx.x;
    const int tid = threadIdx.x;
    if (blk < 768) {
        // row gg: 0-255 = i (sg=gg), 256-511 = g (sg=gg+256), 512-767 = o
        const int gg = blk, sg = gg + (gg >= 256 ? 256 : 0);
        // activation pre-scale folded into fused weights: tanh args are
        // i/2, g, o/2, each then /4 for the Pade u = arg/4.
        const float scale = (gg >= 256 && gg < 512) ? 0.25f : 0.125f;
        const float* wr = W_ih + (size_t)sg * 256;
        const int f = tid & 31, r8 = tid >> 5;
        float acc = 0.f;
#pragma unroll
        for (int k = 0; k < 32; ++k) {
            int r = r8 * 32 + k;
            acc = fmaf(wr[r], enc_W[r * 32 + f], acc);
        }
        __shared__ float red[256];
        __shared__ float redb[256];
        __shared__ float red2[32];
        red[tid]  = acc;
        redb[tid] = wr[tid] * enc_b[tid];
        __syncthreads();
        if (tid < 32) {
            float s = 0.f;
#pragma unroll
            for (int k = 0; k < 8; ++k) s += red[k * 32 + tid];
            Mb[gg * 32 + tid] = (_Float16)(s * scale);
        } else if (tid >= 128 && tid < 160) {
            int t2 = tid - 128;
            float s2 = 0.f;
#pragma unroll
            for (int k = 0; k < 8; ++k) s2 += redb[t2 * 8 + k];
            red2[t2] = s2;
        }
        __syncthreads();
        if (tid == 0) {
            float t = b_ih[sg] + b_hh[sg];
#pragma unroll
            for (int k = 0; k < 32; ++k) t += red2[k];
            fb[gg] = t * scale;
        }
    } else {
        // blocks 768..775: dec_W f32 -> f16 (8192 elems, 4/thread)
        int i = (blk - 768) * 1024 + tid * 4;
        f32x4 v = *(const f32x4*)(dec_W + i);
        f16x4 o;
#pragma unroll
        for (int j = 0; j < 4; ++j) o[j] = (_Float16)v[j];
        *(f16x4*)(decWb + i) = o;
    }
}

__global__ __launch_bounds__(256) void lstm_main(
    const float* __restrict__ in, const _Float16* __restrict__ Mb,
    const float* __restrict__ fb, const _Float16* __restrict__ decWb,
    const float* __restrict__ dec_b, float* __restrict__ out) {
    // per-wave LDS: h tile [2 s][16 t][40 f16] (pitch 40: 2-way alias = free)
    __shared__ _Float16 hbuf[4][2][16 * 40];

    const int lane = threadIdx.x & 63;
    const int w    = threadIdx.x >> 6;
    const int l16  = lane & 15;
    const int q    = lane >> 4;
    const int wave = blockIdx.x * 4 + w;
    const int rowbase = wave * 32;            // 2112 % 32 == 0: one b per wave
    const int b  = rowbase / TT;
    const int t0 = rowbase - b * TT;

    // Pade[7/6] tanh(4u) coefficients (u clamped to [-1,1], w = u^2):
    //   num = u*(4 + 7.757576 w + 2.068687 w^2)
    //   den = 1 + 7.272727 w + 5.171717 w^2 + 0.394036 w^3
    const hx2 C0 = splat(4.0f),      C1 = splat(7.757576f), C2 = splat(2.068687f);
    const hx2 D1 = splat(7.272727f), D2 = splat(5.171717f), D3 = splat(0.394036f);
    const hx2 ONE = splat(1.0f), NEG1 = splat(-1.0f), H05 = splat(0.5f);
    // tanh(c)/c for z=c^2 in [0,1]: cubic Chebyshev-node fit, err ~5e-4
    const hx2 T0 = splat(0.99980f), T1 = splat(-0.32806f),
              T2 = splat(0.11306f), T3 = splat(-0.02344f);

    // Input B-fragments: B[k=q*8+j][n=l16] = input[b][min(t,2047)][q*8+j]
    f16x8 bfr[2];
#pragma unroll
    for (int s = 0; s < 2; ++s) {
        int t  = t0 + s * 16 + l16;
        int tr = t < T_IN ? t : (T_IN - 1);
        const float* p = in + ((size_t)(b * T_IN + tr)) * FIN + q * 8;
        f32x4 u0 = *(const f32x4*)(p);
        f32x4 u1 = *(const f32x4*)(p + 4);
        union { hx2 h[4]; f16x8 v; } pk;
        pk.h[0] = pk2(u0[0], u0[1]); pk.h[1] = pk2(u0[2], u0[3]);
        pk.h[2] = pk2(u1[0], u1[1]); pk.h[3] = pk2(u1[2], u1[3]);
        bfr[s] = pk.v;
    }

    // decoder acc starts at dec_b (rides the MFMA C operand)
    f32x4 dacc[2][2];
#pragma unroll
    for (int ot = 0; ot < 2; ++ot) {
        f32x4 db = *(const f32x4*)(dec_b + ot * 16 + q * 4);
        dacc[0][ot] = db; dacc[1][ot] = db;
    }

    for (int hc = 0; hc < 8; ++hc) {
        const int hb = hc * 32;
        // Gate weight A-frags + bias C-frags
        f16x8 afr[3][2];
        f32x4 fbv[3][2];
#pragma unroll
        for (int gt = 0; gt < 3; ++gt)
#pragma unroll
            for (int X = 0; X < 2; ++X) {
                int grow = gt * 256 + hb + X * 16;
                afr[gt][X] = *(const f16x8*)(Mb + (size_t)(grow + l16) * 32 + q * 8);
                fbv[gt][X] = *(const f32x4*)(fb + grow + q * 4);
            }
        // Decoder A-frags: A2[m=ot*16+l16][k -> hid=hb+q*8+j]
        f16x8 a2[2];
#pragma unroll
        for (int ot = 0; ot < 2; ++ot)
            a2[ot] = *(const f16x8*)(decWb + (size_t)(ot * 16 + l16) * 256 + hb + q * 8);

#pragma unroll
        for (int s = 0; s < 2; ++s) {
            // D[m = gate hid][n = t]; pre-scaled bias rides the C operand.
            // Gate values arrive pre-scaled: i/8, g/4, o/8 == Pade u args.
            f32x4 gi[2], gg[2], go[2];
#pragma unroll
            for (int X = 0; X < 2; ++X) {
                gi[X] = __builtin_amdgcn_mfma_f32_16x16x32_f16(afr[0][X], bfr[s], fbv[0][X], 0, 0, 0);
                gg[X] = __builtin_amdgcn_mfma_f32_16x16x32_f16(afr[1][X], bfr[s], fbv[1][X], 0, 0, 0);
                go[X] = __builtin_amdgcn_mfma_f32_16x16x32_f16(afr[2][X], bfr[s], fbv[2][X], 0, 0, 0);
            }
            _Float16* hp = &hbuf[w][s][0];
#pragma unroll
            for (int X = 0; X < 2; ++X) {
                hx2 hpair[2];
#pragma unroll
                for (int p = 0; p < 2; ++p) {
                    // pack 2 elems; all math below is v_pk_* f16 (2/instr)
                    hx2 ui = pk2(gi[X][2 * p], gi[X][2 * p + 1]);
                    hx2 ug = pk2(gg[X][2 * p], gg[X][2 * p + 1]);
                    hx2 uo = pk2(go[X][2 * p], go[X][2 * p + 1]);
                    ui = __builtin_elementwise_max(__builtin_elementwise_min(ui, ONE), NEG1);
                    ug = __builtin_elementwise_max(__builtin_elementwise_min(ug, ONE), NEG1);
                    uo = __builtin_elementwise_max(__builtin_elementwise_min(uo, ONE), NEG1);
                    hx2 wi = ui * ui, wg = ug * ug, wo = uo * uo;
                    hx2 ni = ui * (wi * (wi * C2 + C1) + C0);
                    hx2 ng = ug * (wg * (wg * C2 + C1) + C0);
                    hx2 no = uo * (wo * (wo * C2 + C1) + C0);
                    hx2 di = wi * (wi * (wi * D3 + D2) + D1) + ONE;
                    hx2 dg = wg * (wg * (wg * D3 + D2) + D1) + ONE;
                    hx2 dd = wo * (wo * (wo * D3 + D2) + D1) + ONE;
                    // one rcp for all three denominators (per 2 elems, f32)
                    hx2 pig = di * dg;
                    hx2 Dp  = pig * dd;
                    hx2 R   = pk2(__builtin_amdgcn_rcpf((float)Dp.x),
                                  __builtin_amdgcn_rcpf((float)Dp.y));
                    hx2 ti = ni * ((dg * dd) * R);   // tanh(i/2)
                    hx2 tg = ng * ((di * dd) * R);   // tanh(g)
                    hx2 to = no * (pig * R);         // tanh(o/2)
                    hx2 si = ti * H05 + H05;         // sigmoid(i)
                    hx2 so = to * H05 + H05;         // sigmoid(o)
                    hx2 c  = si * tg;
                    hx2 z  = c * c;
                    hx2 P  = z * (z * (z * T3 + T2) + T1) + T0;
                    hpair[p] = so * (c * P);         // h = sigmoid(o)*tanh(c)
                }
                // h already packed f16: one 8B LDS write per X
                union { hx2 h[2]; uint2 u; } hw;
                hw.h[0] = hpair[0]; hw.h[1] = hpair[1];
                *(uint2*)(hp + l16 * 40 + X * 16 + q * 4) = hw.u;
            }
            // wave-internal cross-lane LDS handoff
            asm volatile("s_waitcnt lgkmcnt(0)" ::: "memory");
            // B2[k=q*8+j][n=l16] = h[t=l16][hb + q*8+j]
            f16x8 b2 = *(const f16x8*)(hp + l16 * 40 + q * 8);
#pragma unroll
            for (int ot = 0; ot < 2; ++ot)
                dacc[s][ot] = __builtin_amdgcn_mfma_f32_16x16x32_f16(a2[ot], b2, dacc[s][ot], 0, 0, 0);
        }
    }

    // D2[od = ot*16 + 4q + r][t=l16] -> out[(b*TT+t)*32 + od], float4 per lane
#pragma unroll
    for (int s = 0; s < 2; ++s) {
        int t = t0 + s * 16 + l16;
        size_t ro = ((size_t)(b * TT + t)) * FOUT;
#pragma unroll
        for (int ot = 0; ot < 2; ++ot)
            *(f32x4*)(out + ro + ot * 16 + q * 4) = dacc[s][ot];
    }
}

extern "C" void kernel_launch(void* const* d_in, const int* in_sizes, int n_in,
                              void* d_out, int out_size, void* d_ws, size_t ws_size,
                              hipStream_t stream) {
    const float* input = (const float*)d_in[0];
    const float* enc_W = (const float*)d_in[1];
    const float* enc_b = (const float*)d_in[2];
    const float* W_ih  = (const float*)d_in[3];
    // d_in[4] = W_hh: unused (h0 = 0 -> state_gates = b_hh only)
    const float* b_ih  = (const float*)d_in[5];
    const float* b_hh  = (const float*)d_in[6];
    const float* dec_W = (const float*)d_in[7];
    const float* dec_b = (const float*)d_in[8];
    // d_in[9] = future_n (fixed 64, baked into TT)

    _Float16* Mb    = (_Float16*)d_ws;
    float*    fb    = (float*)((char*)d_ws + WS_FB_OFF);
    _Float16* decWb = (_Float16*)((char*)d_ws + WS_DECW_OFF);
    float*    out   = (float*)d_out;

    prep2<<<776, 256, 0, stream>>>(enc_W, enc_b, W_ih, b_ih, b_hh, dec_W, Mb, fb, decWb);
    // 128 b * 2112 t rows / 32 rows-per-wave = 8448 waves; 4 waves/block
    lstm_main<<<2112, 256, 0, stream>>>(input, Mb, fb, decWb, dec_b, out);
}